// Round 1
// baseline (1658.554 us; speedup 1.0000x reference)
//
#include <hip/hip_runtime.h>
#include <hip/hip_bf16.h>
#include <math.h>

#define N_NODES 20000
#define N_EDGES 320000
#define DIM_IN 768
#define DIM_H 512
#define NUM_GNNS 4
#define NEG_SLOPE 0.2f

__device__ __forceinline__ float waveReduceSum(float v) {
#pragma unroll
  for (int off = 32; off > 0; off >>= 1) v += __shfl_xor(v, off, 64);
  return v;
}
__device__ __forceinline__ float waveReduceMax(float v) {
#pragma unroll
  for (int off = 32; off > 0; off >>= 1) v = fmaxf(v, __shfl_xor(v, off, 64));
  return v;
}

// ---------------- GEMM: C[M,N] = A[M,K] @ B[K,N] (+ bias) ----------------
#define BM 64
#define BN 64
#define BK 16

__global__ __launch_bounds__(256) void gemm_bias_kernel(
    const float* __restrict__ A, const float* __restrict__ B,
    const float* __restrict__ bias, float* __restrict__ C,
    int M, int N, int K) {
  __shared__ float As[BK][BM + 4];
  __shared__ float Bs[BK][BN + 4];
  int tid = threadIdx.x;
  int tx = tid & 15;   // N direction (x4)
  int ty = tid >> 4;   // M direction (x4)
  int bm = blockIdx.y * BM;
  int bn = blockIdx.x * BN;
  float acc[4][4] = {};

  int am = tid >> 2;         // 0..63 (row within A tile)
  int ak = (tid & 3) * 4;    // 0,4,8,12
  int bk = tid >> 4;         // 0..15 (row within B tile)
  int bn4 = (tid & 15) * 4;  // 0..60

  for (int k0 = 0; k0 < K; k0 += BK) {
    int row = bm + am;
    float4 av = make_float4(0.f, 0.f, 0.f, 0.f);
    if (row < M) av = *(const float4*)(A + (size_t)row * K + k0 + ak);
    As[ak + 0][am] = av.x;
    As[ak + 1][am] = av.y;
    As[ak + 2][am] = av.z;
    As[ak + 3][am] = av.w;
    float4 bv = *(const float4*)(B + (size_t)(k0 + bk) * N + bn + bn4);
    *(float4*)&Bs[bk][bn4] = bv;
    __syncthreads();
#pragma unroll
    for (int kk = 0; kk < BK; ++kk) {
      float a[4], b[4];
#pragma unroll
      for (int i = 0; i < 4; ++i) a[i] = As[kk][ty * 4 + i];
#pragma unroll
      for (int j = 0; j < 4; ++j) b[j] = Bs[kk][tx * 4 + j];
#pragma unroll
      for (int i = 0; i < 4; ++i)
#pragma unroll
        for (int j = 0; j < 4; ++j) acc[i][j] += a[i] * b[j];
    }
    __syncthreads();
  }

  float4 bb = make_float4(0.f, 0.f, 0.f, 0.f);
  if (bias) bb = *(const float4*)(bias + bn + tx * 4);
#pragma unroll
  for (int i = 0; i < 4; ++i) {
    int row = bm + ty * 4 + i;
    if (row < M) {
      float4 o;
      o.x = acc[i][0] + bb.x;
      o.y = acc[i][1] + bb.y;
      o.z = acc[i][2] + bb.z;
      o.w = acc[i][3] + bb.w;
      *(float4*)(C + (size_t)row * N + bn + tx * 4) = o;
    }
  }
}

// ---------------- CSR build (dst -> src adjacency) ----------------
__global__ void count_edges(const int* __restrict__ dst, int* __restrict__ counts) {
  int k = blockIdx.x * blockDim.x + threadIdx.x;
  if (k < N_EDGES) atomicAdd(&counts[dst[k]], 1);
}

__global__ __launch_bounds__(1024) void scan_kernel(const int* __restrict__ counts,
                                                    int* __restrict__ indptr) {
  __shared__ int part[1024];
  int tid = threadIdx.x;
  const int CH = (N_NODES + 1023) / 1024;  // 20
  int base = tid * CH;
  int s = 0;
  for (int i = 0; i < CH; ++i) {
    int idx = base + i;
    if (idx < N_NODES) s += counts[idx];
  }
  part[tid] = s;
  __syncthreads();
  for (int off = 1; off < 1024; off <<= 1) {
    int v = (tid >= off) ? part[tid - off] : 0;
    __syncthreads();
    part[tid] += v;
    __syncthreads();
  }
  int run = (tid == 0) ? 0 : part[tid - 1];
  for (int i = 0; i < CH; ++i) {
    int idx = base + i;
    if (idx < N_NODES) {
      indptr[idx] = run;
      run += counts[idx];
      if (idx == N_NODES - 1) indptr[N_NODES] = run;
    }
  }
}

__global__ void fill_adj(const int* __restrict__ src, const int* __restrict__ dst,
                         const int* __restrict__ indptr, int* __restrict__ cursor,
                         int* __restrict__ adjsrc) {
  int k = blockIdx.x * blockDim.x + threadIdx.x;
  if (k < N_EDGES) {
    int d = dst[k];
    int pos = atomicAdd(&cursor[d], 1);
    adjsrc[indptr[d] + pos] = src[k];
  }
}

// ---------------- el/er: per-node dot products ----------------
__global__ __launch_bounds__(256) void eler_kernel(const float* __restrict__ z,
                                                   const float* __restrict__ al,
                                                   const float* __restrict__ ar,
                                                   float* __restrict__ el,
                                                   float* __restrict__ er) {
  int wid = (blockIdx.x * blockDim.x + threadIdx.x) >> 6;
  int lane = threadIdx.x & 63;
  if (wid >= N_NODES) return;
  const float4* zr = (const float4*)(z + (size_t)wid * DIM_H);
  const float4* al4 = (const float4*)al;
  const float4* ar4 = (const float4*)ar;
  float4 z0 = zr[lane], z1 = zr[64 + lane];
  float4 a0 = al4[lane], a1 = al4[64 + lane];
  float4 r0 = ar4[lane], r1 = ar4[64 + lane];
  float sl = z0.x * a0.x + z0.y * a0.y + z0.z * a0.z + z0.w * a0.w +
             z1.x * a1.x + z1.y * a1.y + z1.z * a1.z + z1.w * a1.w;
  float sr = z0.x * r0.x + z0.y * r0.y + z0.z * r0.z + z0.w * r0.w +
             z1.x * r1.x + z1.y * r1.y + z1.z * r1.z + z1.w * r1.w;
  sl = waveReduceSum(sl);
  sr = waveReduceSum(sr);
  if (lane == 0) {
    el[wid] = sl;
    er[wid] = sr;
  }
}

// ---------------- GAT edge-softmax + aggregate (wave per dst node) ----------------
__global__ __launch_bounds__(256) void gat_aggregate(
    const float* __restrict__ z, const float* __restrict__ el,
    const float* __restrict__ er, const int* __restrict__ indptr,
    const int* __restrict__ adjsrc, const float* __restrict__ bias,
    float* __restrict__ out) {
  int v = (blockIdx.x * blockDim.x + threadIdx.x) >> 6;
  int lane = threadIdx.x & 63;
  if (v >= N_NODES) return;
  int begin = indptr[v], end = indptr[v + 1];
  float er_v = er[v];

  float m = -INFINITY;
  for (int j = begin + lane; j < end; j += 64) {
    float e = el[adjsrc[j]] + er_v;
    e = (e >= 0.f) ? e : NEG_SLOPE * e;
    m = fmaxf(m, e);
  }
  m = waveReduceMax(m);

  float ssum = 0.f;
  for (int j = begin + lane; j < end; j += 64) {
    float e = el[adjsrc[j]] + er_v;
    e = (e >= 0.f) ? e : NEG_SLOPE * e;
    ssum += __expf(e - m);
  }
  float denom = waveReduceSum(ssum);
  float inv = (end > begin) ? 1.f / denom : 0.f;

  float4 acc0 = make_float4(0.f, 0.f, 0.f, 0.f);
  float4 acc1 = make_float4(0.f, 0.f, 0.f, 0.f);
  for (int j = begin; j < end; ++j) {
    int s = adjsrc[j];
    float e = el[s] + er_v;
    e = (e >= 0.f) ? e : NEG_SLOPE * e;
    float w = __expf(e - m) * inv;
    const float4* zr = (const float4*)(z + (size_t)s * DIM_H);
    float4 z0 = zr[lane], z1 = zr[64 + lane];
    acc0.x += w * z0.x; acc0.y += w * z0.y; acc0.z += w * z0.z; acc0.w += w * z0.w;
    acc1.x += w * z1.x; acc1.y += w * z1.y; acc1.z += w * z1.z; acc1.w += w * z1.w;
  }
  const float4* b4 = (const float4*)bias;
  float4 b0 = b4[lane], b1 = b4[64 + lane];
  float4 o0 = make_float4(acc0.x + b0.x, acc0.y + b0.y, acc0.z + b0.z, acc0.w + b0.w);
  float4 o1 = make_float4(acc1.x + b1.x, acc1.y + b1.y, acc1.z + b1.z, acc1.w + b1.w);
  float4* outr = (float4*)(out + (size_t)v * DIM_H);
  outr[lane] = o0;
  outr[64 + lane] = o1;
}

// ---------------- A_hat propagation hop: out[v] = in[v] + sum_{src->v} in[src] ----------------
__global__ __launch_bounds__(256) void propagate_kernel(const float* __restrict__ zin,
                                                        const int* __restrict__ indptr,
                                                        const int* __restrict__ adjsrc,
                                                        float* __restrict__ out) {
  int v = (blockIdx.x * blockDim.x + threadIdx.x) >> 6;
  int lane = threadIdx.x & 63;
  if (v >= N_NODES) return;
  const float4* self = (const float4*)(zin + (size_t)v * DIM_H);
  float4 acc0 = self[lane], acc1 = self[64 + lane];
  int begin = indptr[v], end = indptr[v + 1];
  for (int j = begin; j < end; ++j) {
    const float4* zr = (const float4*)(zin + (size_t)adjsrc[j] * DIM_H);
    float4 z0 = zr[lane], z1 = zr[64 + lane];
    acc0.x += z0.x; acc0.y += z0.y; acc0.z += z0.z; acc0.w += z0.w;
    acc1.x += z1.x; acc1.y += z1.y; acc1.z += z1.z; acc1.w += z1.w;
  }
  float4* outr = (float4*)(out + (size_t)v * DIM_H);
  outr[lane] = acc0;
  outr[64 + lane] = acc1;
}

extern "C" void kernel_launch(void* const* d_in, const int* in_sizes, int n_in,
                              void* d_out, int out_size, void* d_ws, size_t ws_size,
                              hipStream_t stream) {
  const float* feat = (const float*)d_in[0];
  const float* fc_W = (const float*)d_in[1];
  const float* fc_b = (const float*)d_in[2];
  const float* gat_W = (const float*)d_in[3];
  const float* gat_al = (const float*)d_in[4];
  const float* gat_ar = (const float*)d_in[5];
  const float* gat_b = (const float*)d_in[6];
  // d_in[7] = beta: not needed (reference returns Z_prev, beta only affects unused Z)
  const int* src = (const int*)d_in[8];
  const int* dst = (const int*)d_in[9];
  float* out = (float*)d_out;

  // workspace layout
  float* bufA = (float*)d_ws;                       // N*DIM_H
  float* el = bufA + (size_t)N_NODES * DIM_H;       // N
  float* er = el + N_NODES;                         // N
  int* counts = (int*)(er + N_NODES);               // N
  int* cursor = counts + N_NODES;                   // N
  int* indptr = cursor + N_NODES;                   // N+1
  int* adjsrc = indptr + (N_NODES + 1);             // E
  float* zbuf = out;                                // reuse d_out as z/ping buffer

  // --- build CSR (dst -> list of src) ---
  hipMemsetAsync(counts, 0, sizeof(int) * 2 * N_NODES, stream);
  count_edges<<<(N_EDGES + 255) / 256, 256, 0, stream>>>(dst, counts);
  scan_kernel<<<1, 1024, 0, stream>>>(counts, indptr);
  fill_adj<<<(N_EDGES + 255) / 256, 256, 0, stream>>>(src, dst, indptr, cursor, adjsrc);

  dim3 ggrid(DIM_H / BN, (N_NODES + BM - 1) / BM);

  // h = feat @ fc_W + fc_b
  gemm_bias_kernel<<<ggrid, 256, 0, stream>>>(feat, fc_W, fc_b, bufA, N_NODES, DIM_H, DIM_IN);

  int nwaveblocks = (N_NODES * 64 + 255) / 256;
  for (int l = 0; l < NUM_GNNS; ++l) {
    const float* W = gat_W + (size_t)l * DIM_H * DIM_H;
    gemm_bias_kernel<<<ggrid, 256, 0, stream>>>(bufA, W, nullptr, zbuf, N_NODES, DIM_H, DIM_H);
    eler_kernel<<<nwaveblocks, 256, 0, stream>>>(zbuf, gat_al + (size_t)l * DIM_H,
                                                 gat_ar + (size_t)l * DIM_H, el, er);
    gat_aggregate<<<nwaveblocks, 256, 0, stream>>>(zbuf, el, er, indptr, adjsrc,
                                                   gat_b + (size_t)l * DIM_H, bufA);
  }

  // 3 propagation hops; final hop lands in d_out
  propagate_kernel<<<nwaveblocks, 256, 0, stream>>>(bufA, indptr, adjsrc, zbuf);
  propagate_kernel<<<nwaveblocks, 256, 0, stream>>>(zbuf, indptr, adjsrc, bufA);
  propagate_kernel<<<nwaveblocks, 256, 0, stream>>>(bufA, indptr, adjsrc, out);
}

// Round 3
// 844.341 us; speedup vs baseline: 1.9643x; 1.9643x over previous
//
#include <hip/hip_runtime.h>
#include <math.h>

#define N_NODES 20000
#define M_PAD   20096   // 157 * 128
#define N_EDGES 320000
#define DIM_IN 768
#define DIM_H 512
#define NUM_GNNS 4
#define NEG_SLOPE 0.2f

typedef __attribute__((ext_vector_type(8))) short short8;
typedef __attribute__((ext_vector_type(4))) float f32x4;

#define GPTR(p) (const __attribute__((address_space(1))) void*)(p)
#define LPTR(p) (__attribute__((address_space(3))) void*)(p)

__device__ __forceinline__ float bf2f(unsigned int lo16) {
  return __uint_as_float(lo16 << 16);
}
__device__ __forceinline__ unsigned short f2bf(float f) {
  unsigned int u = __float_as_uint(f);
  u += 0x7FFFu + ((u >> 16) & 1u);   // round-to-nearest-even
  return (unsigned short)(u >> 16);
}
__device__ __forceinline__ void unpack8(uint4 v, float* f) {
  f[0] = bf2f(v.x & 0xffffu); f[1] = bf2f(v.x >> 16);
  f[2] = bf2f(v.y & 0xffffu); f[3] = bf2f(v.y >> 16);
  f[4] = bf2f(v.z & 0xffffu); f[5] = bf2f(v.z >> 16);
  f[6] = bf2f(v.w & 0xffffu); f[7] = bf2f(v.w >> 16);
}

__device__ __forceinline__ float waveReduceSum(float v) {
#pragma unroll
  for (int off = 32; off > 0; off >>= 1) v += __shfl_xor(v, off, 64);
  return v;
}
__device__ __forceinline__ float waveReduceMax(float v) {
#pragma unroll
  for (int off = 32; off > 0; off >>= 1) v = fmaxf(v, __shfl_xor(v, off, 64));
  return v;
}

// ================= MFMA GEMM: Cbf[M_PAD,512](bf16) = A[M_PAD,K](bf16) @ Bt[512,K]^T (+bias) =====
// 128x128 tile, TK=32, 4 waves (2x2 of 64x64), 16x16x32 bf16 MFMA.
// LDS staged via global_load_lds width=16 with xor swizzle:
//   element (row, kc) lives at LDS slot row*32 + 8*(kc ^ ((row>>1)&3))
__global__ __launch_bounds__(256) void gemm_mfma_bf16(
    const unsigned short* __restrict__ A,
    const unsigned short* __restrict__ Bt,
    const float* __restrict__ bias,
    unsigned short* __restrict__ Cbf,
    int K) {
  __shared__ __align__(16) unsigned short As[128 * 32];
  __shared__ __align__(16) unsigned short Bs[128 * 32];
  int tid = threadIdx.x;
  int wave = tid >> 6, lane = tid & 63;
  int wm = wave >> 1, wn = wave & 1;

  // ---- staging addresses: wave stages rows [32*wave, 32*wave+32) of both tiles (2 insts each)
  int rl = lane >> 2;                          // row within 16-row window
  int kc = (lane & 3) ^ ((lane >> 3) & 3);     // swizzled k-chunk to fetch
  int r0 = 32 * wave;
  const unsigned short* gA0 = A + (size_t)(blockIdx.y * 128 + r0 + rl) * K + kc * 8;
  const unsigned short* gA1 = gA0 + (size_t)16 * K;
  const unsigned short* gB0 = Bt + (size_t)(blockIdx.x * 128 + r0 + rl) * K + kc * 8;
  const unsigned short* gB1 = gB0 + (size_t)16 * K;
  unsigned short* lA0 = As + r0 * 32;
  unsigned short* lA1 = As + (r0 + 16) * 32;
  unsigned short* lB0 = Bs + r0 * 32;
  unsigned short* lB1 = Bs + (r0 + 16) * 32;

  // ---- ds_read bases (conflict-free under the swizzle: 2 lanes/bank)
  int mrow = lane & 15;
  int q = lane >> 4;
  int swz = (q ^ ((mrow >> 1) & 3)) * 8;
  const short8* ra = (const short8*)(As + (64 * wm + mrow) * 32 + swz);
  const short8* rb = (const short8*)(Bs + (64 * wn + mrow) * 32 + swz);

  f32x4 acc[4][4];
#pragma unroll
  for (int i = 0; i < 4; ++i)
#pragma unroll
    for (int j = 0; j < 4; ++j) acc[i][j] = (f32x4)(0.f);

  for (int k0 = 0; k0 < K; k0 += 32) {
    __syncthreads();
    __builtin_amdgcn_global_load_lds(GPTR(gA0 + k0), LPTR(lA0), 16, 0, 0);
    __builtin_amdgcn_global_load_lds(GPTR(gA1 + k0), LPTR(lA1), 16, 0, 0);
    __builtin_amdgcn_global_load_lds(GPTR(gB0 + k0), LPTR(lB0), 16, 0, 0);
    __builtin_amdgcn_global_load_lds(GPTR(gB1 + k0), LPTR(lB1), 16, 0, 0);
    __syncthreads();
    short8 a[4], b[4];
#pragma unroll
    for (int t = 0; t < 4; ++t) a[t] = ra[t * 64];   // +16 rows = +1024 B
#pragma unroll
    for (int t = 0; t < 4; ++t) b[t] = rb[t * 64];
#pragma unroll
    for (int mt = 0; mt < 4; ++mt)
#pragma unroll
      for (int nt = 0; nt < 4; ++nt)
        acc[mt][nt] = __builtin_amdgcn_mfma_f32_16x16x32_bf16(a[mt], b[nt], acc[mt][nt], 0, 0, 0);
  }

  // ---- epilogue: C/D layout col=lane&15, row=4*q+reg
  int colb = blockIdx.x * 128 + 64 * wn + (lane & 15);
  int rowb = blockIdx.y * 128 + 64 * wm + 4 * q;
#pragma unroll
  for (int nt = 0; nt < 4; ++nt) {
    int col = colb + 16 * nt;
    float bv = bias ? bias[col] : 0.f;
#pragma unroll
    for (int mt = 0; mt < 4; ++mt) {
      int row = rowb + 16 * mt;
#pragma unroll
      for (int i = 0; i < 4; ++i)
        Cbf[(size_t)(row + i) * DIM_H + col] = f2bf(acc[mt][nt][i] + bv);
    }
  }
}

// ================= conversions =================
__global__ void convert_feat(const float* __restrict__ feat, unsigned short* __restrict__ Abf) {
  int t = blockIdx.x * blockDim.x + threadIdx.x;  // one 8-element chunk
  const int CHUNKS = M_PAD * DIM_IN / 8;
  if (t >= CHUNKS) return;
  int row = t / (DIM_IN / 8);
  uint4 o;
  if (row < N_NODES) {
    const float4* p = (const float4*)(feat + (size_t)t * 8);
    float4 x = p[0], y = p[1];
    o.x = (unsigned)f2bf(x.x) | ((unsigned)f2bf(x.y) << 16);
    o.y = (unsigned)f2bf(x.z) | ((unsigned)f2bf(x.w) << 16);
    o.z = (unsigned)f2bf(y.x) | ((unsigned)f2bf(y.y) << 16);
    o.w = (unsigned)f2bf(y.z) | ((unsigned)f2bf(y.w) << 16);
  } else {
    o = make_uint4(0, 0, 0, 0);
  }
  ((uint4*)Abf)[t] = o;
}

// in [R,C] f32 -> out [C,R] bf16 ; blockIdx.z batches independent matrices
__global__ void transpose_bf16(const float* __restrict__ in, unsigned short* __restrict__ out,
                               int R, int C) {
  int r = blockIdx.x * blockDim.x + threadIdx.x;
  int c = blockIdx.y;
  size_t base = (size_t)blockIdx.z * R * C;
  if (r < R) out[base + (size_t)c * R + r] = f2bf(in[base + (size_t)r * C + c]);
}

// ================= CSR build (dst -> src adjacency) =================
__global__ void count_edges(const int* __restrict__ dst, int* __restrict__ counts) {
  int k = blockIdx.x * blockDim.x + threadIdx.x;
  if (k < N_EDGES) atomicAdd(&counts[dst[k]], 1);
}

__global__ __launch_bounds__(1024) void scan_kernel(const int* __restrict__ counts,
                                                    int* __restrict__ indptr) {
  __shared__ int part[1024];
  int tid = threadIdx.x;
  const int CH = (N_NODES + 1023) / 1024;
  int base = tid * CH;
  int s = 0;
  for (int i = 0; i < CH; ++i) {
    int idx = base + i;
    if (idx < N_NODES) s += counts[idx];
  }
  part[tid] = s;
  __syncthreads();
  for (int off = 1; off < 1024; off <<= 1) {
    int v = (tid >= off) ? part[tid - off] : 0;
    __syncthreads();
    part[tid] += v;
    __syncthreads();
  }
  int run = (tid == 0) ? 0 : part[tid - 1];
  for (int i = 0; i < CH; ++i) {
    int idx = base + i;
    if (idx < N_NODES) {
      indptr[idx] = run;
      run += counts[idx];
      if (idx == N_NODES - 1) indptr[N_NODES] = run;
    }
  }
}

__global__ void fill_adj(const int* __restrict__ src, const int* __restrict__ dst,
                         const int* __restrict__ indptr, int* __restrict__ cursor,
                         int* __restrict__ adjsrc) {
  int k = blockIdx.x * blockDim.x + threadIdx.x;
  if (k < N_EDGES) {
    int d = dst[k];
    int pos = atomicAdd(&cursor[d], 1);
    adjsrc[indptr[d] + pos] = src[k];
  }
}

// ================= el/er from bf16 z =================
__global__ __launch_bounds__(256) void eler_bf(const unsigned short* __restrict__ zbf,
                                               const float* __restrict__ al,
                                               const float* __restrict__ ar,
                                               float* __restrict__ el, float* __restrict__ er) {
  int wid = (blockIdx.x * blockDim.x + threadIdx.x) >> 6;
  int lane = threadIdx.x & 63;
  if (wid >= N_NODES) return;
  uint4 zv = ((const uint4*)(zbf + (size_t)wid * DIM_H))[lane];
  float z[8];
  unpack8(zv, z);
  const float4* al4 = (const float4*)(al + lane * 8);
  const float4* ar4 = (const float4*)(ar + lane * 8);
  float4 a0 = al4[0], a1 = al4[1], r0 = ar4[0], r1 = ar4[1];
  float sl = z[0] * a0.x + z[1] * a0.y + z[2] * a0.z + z[3] * a0.w +
             z[4] * a1.x + z[5] * a1.y + z[6] * a1.z + z[7] * a1.w;
  float sr = z[0] * r0.x + z[1] * r0.y + z[2] * r0.z + z[3] * r0.w +
             z[4] * r1.x + z[5] * r1.y + z[6] * r1.z + z[7] * r1.w;
  sl = waveReduceSum(sl);
  sr = waveReduceSum(sr);
  if (lane == 0) { el[wid] = sl; er[wid] = sr; }
}

// ================= GAT edge softmax + aggregate (wave per dst), bf16 payload =================
__global__ __launch_bounds__(256) void gat_aggregate_bf(
    const unsigned short* __restrict__ zbf, const float* __restrict__ el,
    const float* __restrict__ er, const int* __restrict__ indptr,
    const int* __restrict__ adjsrc, const float* __restrict__ bias,
    unsigned short* __restrict__ out_bf, float* __restrict__ out_f32) {
  int v = (blockIdx.x * blockDim.x + threadIdx.x) >> 6;
  int lane = threadIdx.x & 63;
  if (v >= N_NODES) return;
  int begin = indptr[v], end = indptr[v + 1];
  float er_v = er[v];

  float m = -INFINITY;
  for (int j = begin + lane; j < end; j += 64) {
    float e = el[adjsrc[j]] + er_v;
    e = (e >= 0.f) ? e : NEG_SLOPE * e;
    m = fmaxf(m, e);
  }
  m = waveReduceMax(m);

  float ssum = 0.f;
  for (int j = begin + lane; j < end; j += 64) {
    float e = el[adjsrc[j]] + er_v;
    e = (e >= 0.f) ? e : NEG_SLOPE * e;
    ssum += __expf(e - m);
  }
  float denom = waveReduceSum(ssum);
  float inv = (end > begin) ? 1.f / denom : 0.f;

  float acc[8] = {};
  for (int j = begin; j < end; ++j) {
    int s = adjsrc[j];
    float e = el[s] + er_v;
    e = (e >= 0.f) ? e : NEG_SLOPE * e;
    float w = __expf(e - m) * inv;
    uint4 zv = ((const uint4*)(zbf + (size_t)s * DIM_H))[lane];
    float z[8];
    unpack8(zv, z);
#pragma unroll
    for (int i = 0; i < 8; ++i) acc[i] += w * z[i];
  }
  const float4* b4 = (const float4*)(bias + lane * 8);
  float4 b0 = b4[0], b1 = b4[1];
  float o[8] = {acc[0] + b0.x, acc[1] + b0.y, acc[2] + b0.z, acc[3] + b0.w,
                acc[4] + b1.x, acc[5] + b1.y, acc[6] + b1.z, acc[7] + b1.w};
  if (out_bf) {
    uint4 pv;
    pv.x = (unsigned)f2bf(o[0]) | ((unsigned)f2bf(o[1]) << 16);
    pv.y = (unsigned)f2bf(o[2]) | ((unsigned)f2bf(o[3]) << 16);
    pv.z = (unsigned)f2bf(o[4]) | ((unsigned)f2bf(o[5]) << 16);
    pv.w = (unsigned)f2bf(o[6]) | ((unsigned)f2bf(o[7]) << 16);
    ((uint4*)(out_bf + (size_t)v * DIM_H))[lane] = pv;
  }
  if (out_f32) {
    float4* fr = (float4*)(out_f32 + (size_t)v * DIM_H + lane * 8);
    fr[0] = make_float4(o[0], o[1], o[2], o[3]);
    fr[1] = make_float4(o[4], o[5], o[6], o[7]);
  }
}

// ================= A_hat hop: out[v] = in[v] + sum_{src->v} in[src] (fp32) =================
__global__ __launch_bounds__(256) void propagate_kernel(const float* __restrict__ zin,
                                                        const int* __restrict__ indptr,
                                                        const int* __restrict__ adjsrc,
                                                        float* __restrict__ out) {
  int v = (blockIdx.x * blockDim.x + threadIdx.x) >> 6;
  int lane = threadIdx.x & 63;
  if (v >= N_NODES) return;
  const float4* self = (const float4*)(zin + (size_t)v * DIM_H);
  float4 acc0 = self[lane], acc1 = self[64 + lane];
  int begin = indptr[v], end = indptr[v + 1];
  for (int j = begin; j < end; ++j) {
    const float4* zr = (const float4*)(zin + (size_t)adjsrc[j] * DIM_H);
    float4 z0 = zr[lane], z1 = zr[64 + lane];
    acc0.x += z0.x; acc0.y += z0.y; acc0.z += z0.z; acc0.w += z0.w;
    acc1.x += z1.x; acc1.y += z1.y; acc1.z += z1.z; acc1.w += z1.w;
  }
  float4* outr = (float4*)(out + (size_t)v * DIM_H);
  outr[lane] = acc0;
  outr[64 + lane] = acc1;
}

// ================= launch =================
extern "C" void kernel_launch(void* const* d_in, const int* in_sizes, int n_in,
                              void* d_out, int out_size, void* d_ws, size_t ws_size,
                              hipStream_t stream) {
  const float* feat = (const float*)d_in[0];
  const float* fc_W = (const float*)d_in[1];
  const float* fc_b = (const float*)d_in[2];
  const float* gat_W = (const float*)d_in[3];
  const float* gat_al = (const float*)d_in[4];
  const float* gat_ar = (const float*)d_in[5];
  const float* gat_b = (const float*)d_in[6];
  // d_in[7] = beta unused (reference returns Z_prev)
  const int* src = (const int*)d_in[8];
  const int* dst = (const int*)d_in[9];
  float* out = (float*)d_out;

  // ---- workspace layout (all 256B-aligned) ----
  char* w = (char*)d_ws;
  auto alloc = [&](size_t bytes) {
    char* p = w;
    w += (bytes + 255) & ~(size_t)255;
    return p;
  };
  unsigned short* hbf   = (unsigned short*)alloc((size_t)M_PAD * DIM_H * 2);
  unsigned short* fcWt  = (unsigned short*)alloc((size_t)DIM_H * DIM_IN * 2);
  unsigned short* gatWt = (unsigned short*)alloc((size_t)NUM_GNNS * DIM_H * DIM_H * 2);
  float* el    = (float*)alloc((size_t)N_NODES * 4);
  float* er    = (float*)alloc((size_t)N_NODES * 4);
  // counts+cursor MUST be one contiguous block: a single memset zeroes both.
  // (R2 crash root-cause: 256B-aligned separate allocs left a 128B gap, the
  //  tail of cursor stayed 0xAA-poisoned -> fill_adj OOB scatter -> fault.)
  int* counts  = (int*)alloc((size_t)2 * N_NODES * 4);
  int* cursor  = counts + N_NODES;
  int* indptr  = (int*)alloc((size_t)(N_NODES + 1) * 4);
  int* adjsrc  = (int*)alloc((size_t)N_EDGES * 4);
  // union region: Abf (feat bf16, GEMM0 only) then bufA (fp32 h for propagation)
  char* uni = alloc((size_t)N_NODES * DIM_H * 4);   // 41 MB >= Abf's 30.9 MB
  unsigned short* Abf = (unsigned short*)uni;
  float* bufA = (float*)uni;
  unsigned short* zbf = (unsigned short*)d_out;     // z lives in d_out during GAT layers

  // ---- CSR build ----
  hipMemsetAsync(counts, 0, sizeof(int) * 2 * N_NODES, stream);
  count_edges<<<(N_EDGES + 255) / 256, 256, 0, stream>>>(dst, counts);
  scan_kernel<<<1, 1024, 0, stream>>>(counts, indptr);
  fill_adj<<<(N_EDGES + 255) / 256, 256, 0, stream>>>(src, dst, indptr, cursor, adjsrc);

  // ---- bf16 prep ----
  convert_feat<<<(M_PAD * DIM_IN / 8 + 255) / 256, 256, 0, stream>>>(feat, Abf);
  transpose_bf16<<<dim3((DIM_IN + 255) / 256, DIM_H, 1), 256, 0, stream>>>(fc_W, fcWt, DIM_IN, DIM_H);
  transpose_bf16<<<dim3((DIM_H + 255) / 256, DIM_H, NUM_GNNS), 256, 0, stream>>>(gat_W, gatWt, DIM_H, DIM_H);

  dim3 ggrid(DIM_H / 128, M_PAD / 128);  // (4, 157)

  // h = feat @ fc_W + fc_b  -> hbf (bf16)
  gemm_mfma_bf16<<<ggrid, 256, 0, stream>>>(Abf, fcWt, fc_b, hbf, DIM_IN);

  int nwaveblocks = (N_NODES * 64 + 255) / 256;
  for (int l = 0; l < NUM_GNNS; ++l) {
    gemm_mfma_bf16<<<ggrid, 256, 0, stream>>>(hbf, gatWt + (size_t)l * DIM_H * DIM_H,
                                              nullptr, zbf, DIM_H);
    eler_bf<<<nwaveblocks, 256, 0, stream>>>(zbf, gat_al + (size_t)l * DIM_H,
                                             gat_ar + (size_t)l * DIM_H, el, er);
    gat_aggregate_bf<<<nwaveblocks, 256, 0, stream>>>(
        zbf, el, er, indptr, adjsrc, gat_b + (size_t)l * DIM_H,
        (l < NUM_GNNS - 1) ? hbf : nullptr,
        (l == NUM_GNNS - 1) ? bufA : nullptr);
  }

  // ---- 3 propagation hops (fp32): bufA -> out -> bufA -> out ----
  propagate_kernel<<<nwaveblocks, 256, 0, stream>>>(bufA, indptr, adjsrc, out);
  propagate_kernel<<<nwaveblocks, 256, 0, stream>>>(out, indptr, adjsrc, bufA);
  propagate_kernel<<<nwaveblocks, 256, 0, stream>>>(bufA, indptr, adjsrc, out);
}

// Round 4
// 713.110 us; speedup vs baseline: 2.3258x; 1.1840x over previous
//
#include <hip/hip_runtime.h>
#include <math.h>

#define N_NODES 20000
#define M_PAD   20096   // 157 * 128
#define N_EDGES 320000
#define DIM_IN 768
#define DIM_H 512
#define NUM_GNNS 4
#define NEG_SLOPE 0.2f

typedef __attribute__((ext_vector_type(8))) short short8;
typedef __attribute__((ext_vector_type(4))) float f32x4;

#define GPTR(p) (const __attribute__((address_space(1))) void*)(p)
#define LPTR(p) (__attribute__((address_space(3))) void*)(p)

__device__ __forceinline__ float bf2f(unsigned int lo16) {
  return __uint_as_float(lo16 << 16);
}
__device__ __forceinline__ unsigned short f2bf(float f) {
  unsigned int u = __float_as_uint(f);
  u += 0x7FFFu + ((u >> 16) & 1u);   // round-to-nearest-even
  return (unsigned short)(u >> 16);
}
__device__ __forceinline__ void unpack8(uint4 v, float* f) {
  f[0] = bf2f(v.x & 0xffffu); f[1] = bf2f(v.x >> 16);
  f[2] = bf2f(v.y & 0xffffu); f[3] = bf2f(v.y >> 16);
  f[4] = bf2f(v.z & 0xffffu); f[5] = bf2f(v.z >> 16);
  f[6] = bf2f(v.w & 0xffffu); f[7] = bf2f(v.w >> 16);
}
__device__ __forceinline__ uint4 pack8(const float* o) {
  uint4 pv;
  pv.x = (unsigned)f2bf(o[0]) | ((unsigned)f2bf(o[1]) << 16);
  pv.y = (unsigned)f2bf(o[2]) | ((unsigned)f2bf(o[3]) << 16);
  pv.z = (unsigned)f2bf(o[4]) | ((unsigned)f2bf(o[5]) << 16);
  pv.w = (unsigned)f2bf(o[6]) | ((unsigned)f2bf(o[7]) << 16);
  return pv;
}

__device__ __forceinline__ float waveReduceSum(float v) {
#pragma unroll
  for (int off = 32; off > 0; off >>= 1) v += __shfl_xor(v, off, 64);
  return v;
}
__device__ __forceinline__ float waveReduceMax(float v) {
#pragma unroll
  for (int off = 32; off > 0; off >>= 1) v = fmaxf(v, __shfl_xor(v, off, 64));
  return v;
}

// ================= MFMA GEMM: Cbf[M_PAD,512](bf16) = A[M_PAD,K](bf16) @ Bt[512,K]^T (+bias) =====
// 128x128 tile, TK=32, 4 waves (2x2 of 64x64), 16x16x32 bf16 MFMA.
// LDS staged via global_load_lds width=16 with xor swizzle:
//   element (row, kc) lives at LDS slot row*32 + 8*(kc ^ ((row>>1)&3))
__global__ __launch_bounds__(256) void gemm_mfma_bf16(
    const unsigned short* __restrict__ A,
    const unsigned short* __restrict__ Bt,
    const float* __restrict__ bias,
    unsigned short* __restrict__ Cbf,
    int K) {
  __shared__ __align__(16) unsigned short As[128 * 32];
  __shared__ __align__(16) unsigned short Bs[128 * 32];
  int tid = threadIdx.x;
  int wave = tid >> 6, lane = tid & 63;
  int wm = wave >> 1, wn = wave & 1;

  // ---- staging addresses: wave stages rows [32*wave, 32*wave+32) of both tiles (2 insts each)
  int rl = lane >> 2;                          // row within 16-row window
  int kc = (lane & 3) ^ ((lane >> 3) & 3);     // swizzled k-chunk to fetch
  int r0 = 32 * wave;
  const unsigned short* gA0 = A + (size_t)(blockIdx.y * 128 + r0 + rl) * K + kc * 8;
  const unsigned short* gA1 = gA0 + (size_t)16 * K;
  const unsigned short* gB0 = Bt + (size_t)(blockIdx.x * 128 + r0 + rl) * K + kc * 8;
  const unsigned short* gB1 = gB0 + (size_t)16 * K;
  unsigned short* lA0 = As + r0 * 32;
  unsigned short* lA1 = As + (r0 + 16) * 32;
  unsigned short* lB0 = Bs + r0 * 32;
  unsigned short* lB1 = Bs + (r0 + 16) * 32;

  // ---- ds_read bases (conflict-free under the swizzle: 2 lanes/bank)
  int mrow = lane & 15;
  int q = lane >> 4;
  int swz = (q ^ ((mrow >> 1) & 3)) * 8;
  const short8* ra = (const short8*)(As + (64 * wm + mrow) * 32 + swz);
  const short8* rb = (const short8*)(Bs + (64 * wn + mrow) * 32 + swz);

  f32x4 acc[4][4];
#pragma unroll
  for (int i = 0; i < 4; ++i)
#pragma unroll
    for (int j = 0; j < 4; ++j) acc[i][j] = (f32x4)(0.f);

  for (int k0 = 0; k0 < K; k0 += 32) {
    __syncthreads();
    __builtin_amdgcn_global_load_lds(GPTR(gA0 + k0), LPTR(lA0), 16, 0, 0);
    __builtin_amdgcn_global_load_lds(GPTR(gA1 + k0), LPTR(lA1), 16, 0, 0);
    __builtin_amdgcn_global_load_lds(GPTR(gB0 + k0), LPTR(lB0), 16, 0, 0);
    __builtin_amdgcn_global_load_lds(GPTR(gB1 + k0), LPTR(lB1), 16, 0, 0);
    __syncthreads();
    short8 a[4], b[4];
#pragma unroll
    for (int t = 0; t < 4; ++t) a[t] = ra[t * 64];   // +16 rows = +1024 B
#pragma unroll
    for (int t = 0; t < 4; ++t) b[t] = rb[t * 64];
#pragma unroll
    for (int mt = 0; mt < 4; ++mt)
#pragma unroll
      for (int nt = 0; nt < 4; ++nt)
        acc[mt][nt] = __builtin_amdgcn_mfma_f32_16x16x32_bf16(a[mt], b[nt], acc[mt][nt], 0, 0, 0);
  }

  // ---- epilogue: C/D layout col=lane&15, row=4*q+reg
  int colb = blockIdx.x * 128 + 64 * wn + (lane & 15);
  int rowb = blockIdx.y * 128 + 64 * wm + 4 * q;
#pragma unroll
  for (int nt = 0; nt < 4; ++nt) {
    int col = colb + 16 * nt;
    float bv = bias ? bias[col] : 0.f;
#pragma unroll
    for (int mt = 0; mt < 4; ++mt) {
      int row = rowb + 16 * mt;
#pragma unroll
      for (int i = 0; i < 4; ++i)
        Cbf[(size_t)(row + i) * DIM_H + col] = f2bf(acc[mt][nt][i] + bv);
    }
  }
}

// ================= conversions =================
__global__ void convert_feat(const float* __restrict__ feat, unsigned short* __restrict__ Abf) {
  int t = blockIdx.x * blockDim.x + threadIdx.x;  // one 8-element chunk
  const int CHUNKS = M_PAD * DIM_IN / 8;
  if (t >= CHUNKS) return;
  int row = t / (DIM_IN / 8);
  uint4 o;
  if (row < N_NODES) {
    const float4* p = (const float4*)(feat + (size_t)t * 8);
    float4 x = p[0], y = p[1];
    o.x = (unsigned)f2bf(x.x) | ((unsigned)f2bf(x.y) << 16);
    o.y = (unsigned)f2bf(x.z) | ((unsigned)f2bf(x.w) << 16);
    o.z = (unsigned)f2bf(y.x) | ((unsigned)f2bf(y.y) << 16);
    o.w = (unsigned)f2bf(y.z) | ((unsigned)f2bf(y.w) << 16);
  } else {
    o = make_uint4(0, 0, 0, 0);
  }
  ((uint4*)Abf)[t] = o;
}

// in [R,C] f32 -> out [C,R] bf16 ; blockIdx.z batches independent matrices
__global__ void transpose_bf16(const float* __restrict__ in, unsigned short* __restrict__ out,
                               int R, int C) {
  int r = blockIdx.x * blockDim.x + threadIdx.x;
  int c = blockIdx.y;
  size_t base = (size_t)blockIdx.z * R * C;
  if (r < R) out[base + (size_t)c * R + r] = f2bf(in[base + (size_t)r * C + c]);
}

// ================= CSR build (dst -> src adjacency) =================
__global__ void count_edges(const int* __restrict__ dst, int* __restrict__ counts) {
  int k = blockIdx.x * blockDim.x + threadIdx.x;
  if (k < N_EDGES) atomicAdd(&counts[dst[k]], 1);
}

__global__ __launch_bounds__(1024) void scan_kernel(const int* __restrict__ counts,
                                                    int* __restrict__ indptr) {
  __shared__ int part[1024];
  int tid = threadIdx.x;
  const int CH = (N_NODES + 1023) / 1024;
  int base = tid * CH;
  int s = 0;
  for (int i = 0; i < CH; ++i) {
    int idx = base + i;
    if (idx < N_NODES) s += counts[idx];
  }
  part[tid] = s;
  __syncthreads();
  for (int off = 1; off < 1024; off <<= 1) {
    int v = (tid >= off) ? part[tid - off] : 0;
    __syncthreads();
    part[tid] += v;
    __syncthreads();
  }
  int run = (tid == 0) ? 0 : part[tid - 1];
  for (int i = 0; i < CH; ++i) {
    int idx = base + i;
    if (idx < N_NODES) {
      indptr[idx] = run;
      run += counts[idx];
      if (idx == N_NODES - 1) indptr[N_NODES] = run;
    }
  }
}

__global__ void fill_adj(const int* __restrict__ src, const int* __restrict__ dst,
                         const int* __restrict__ indptr, int* __restrict__ cursor,
                         int* __restrict__ adjsrc) {
  int k = blockIdx.x * blockDim.x + threadIdx.x;
  if (k < N_EDGES) {
    int d = dst[k];
    int pos = atomicAdd(&cursor[d], 1);
    adjsrc[indptr[d] + pos] = src[k];
  }
}

// ================= el/er from bf16 z =================
__global__ __launch_bounds__(256) void eler_bf(const unsigned short* __restrict__ zbf,
                                               const float* __restrict__ al,
                                               const float* __restrict__ ar,
                                               float* __restrict__ el, float* __restrict__ er) {
  int wid = (blockIdx.x * blockDim.x + threadIdx.x) >> 6;
  int lane = threadIdx.x & 63;
  if (wid >= N_NODES) return;
  uint4 zv = ((const uint4*)(zbf + (size_t)wid * DIM_H))[lane];
  float z[8];
  unpack8(zv, z);
  const float4* al4 = (const float4*)(al + lane * 8);
  const float4* ar4 = (const float4*)(ar + lane * 8);
  float4 a0 = al4[0], a1 = al4[1], r0 = ar4[0], r1 = ar4[1];
  float sl = z[0] * a0.x + z[1] * a0.y + z[2] * a0.z + z[3] * a0.w +
             z[4] * a1.x + z[5] * a1.y + z[6] * a1.z + z[7] * a1.w;
  float sr = z[0] * r0.x + z[1] * r0.y + z[2] * r0.z + z[3] * r0.w +
             z[4] * r1.x + z[5] * r1.y + z[6] * r1.z + z[7] * r1.w;
  sl = waveReduceSum(sl);
  sr = waveReduceSum(sr);
  if (lane == 0) { el[wid] = sl; er[wid] = sr; }
}

// ================= GAT edge softmax + aggregate (wave per dst), bf16 payload =================
__global__ __launch_bounds__(256) void gat_aggregate_bf(
    const unsigned short* __restrict__ zbf, const float* __restrict__ el,
    const float* __restrict__ er, const int* __restrict__ indptr,
    const int* __restrict__ adjsrc, const float* __restrict__ bias,
    unsigned short* __restrict__ out_bf) {
  int v = (blockIdx.x * blockDim.x + threadIdx.x) >> 6;
  int lane = threadIdx.x & 63;
  if (v >= N_NODES) return;
  int begin = indptr[v], end = indptr[v + 1];
  float er_v = er[v];

  float m = -INFINITY;
  for (int j = begin + lane; j < end; j += 64) {
    float e = el[adjsrc[j]] + er_v;
    e = (e >= 0.f) ? e : NEG_SLOPE * e;
    m = fmaxf(m, e);
  }
  m = waveReduceMax(m);

  float ssum = 0.f;
  for (int j = begin + lane; j < end; j += 64) {
    float e = el[adjsrc[j]] + er_v;
    e = (e >= 0.f) ? e : NEG_SLOPE * e;
    ssum += __expf(e - m);
  }
  float denom = waveReduceSum(ssum);
  float inv = (end > begin) ? 1.f / denom : 0.f;

  float acc[8] = {};
  for (int j = begin; j < end; ++j) {
    int s = adjsrc[j];
    float e = el[s] + er_v;
    e = (e >= 0.f) ? e : NEG_SLOPE * e;
    float w = __expf(e - m) * inv;
    uint4 zv = ((const uint4*)(zbf + (size_t)s * DIM_H))[lane];
    float z[8];
    unpack8(zv, z);
#pragma unroll
    for (int i = 0; i < 8; ++i) acc[i] += w * z[i];
  }
  const float4* b4 = (const float4*)(bias + lane * 8);
  float4 b0 = b4[0], b1 = b4[1];
  float o[8] = {acc[0] + b0.x, acc[1] + b0.y, acc[2] + b0.z, acc[3] + b0.w,
                acc[4] + b1.x, acc[5] + b1.y, acc[6] + b1.z, acc[7] + b1.w};
  ((uint4*)(out_bf + (size_t)v * DIM_H))[lane] = pack8(o);
}

// ======== A_hat hop (bf16 payload, fp32 accumulate): out[v] = in[v] + sum in[src] ========
// Exactly one of out_bf / out_f32 is non-null.
__global__ __launch_bounds__(256) void propagate_bf(const unsigned short* __restrict__ zin,
                                                    const int* __restrict__ indptr,
                                                    const int* __restrict__ adjsrc,
                                                    unsigned short* __restrict__ out_bf,
                                                    float* __restrict__ out_f32) {
  int v = (blockIdx.x * blockDim.x + threadIdx.x) >> 6;
  int lane = threadIdx.x & 63;
  if (v >= N_NODES) return;
  uint4 sv = ((const uint4*)(zin + (size_t)v * DIM_H))[lane];
  float acc[8];
  unpack8(sv, acc);
  int begin = indptr[v], end = indptr[v + 1];
  for (int j = begin; j < end; ++j) {
    uint4 zv = ((const uint4*)(zin + (size_t)adjsrc[j] * DIM_H))[lane];
    float z[8];
    unpack8(zv, z);
#pragma unroll
    for (int i = 0; i < 8; ++i) acc[i] += z[i];
  }
  if (out_bf) {
    ((uint4*)(out_bf + (size_t)v * DIM_H))[lane] = pack8(acc);
  } else {
    float4* fr = (float4*)(out_f32 + (size_t)v * DIM_H + lane * 8);
    fr[0] = make_float4(acc[0], acc[1], acc[2], acc[3]);
    fr[1] = make_float4(acc[4], acc[5], acc[6], acc[7]);
  }
}

// ================= launch =================
extern "C" void kernel_launch(void* const* d_in, const int* in_sizes, int n_in,
                              void* d_out, int out_size, void* d_ws, size_t ws_size,
                              hipStream_t stream) {
  const float* feat = (const float*)d_in[0];
  const float* fc_W = (const float*)d_in[1];
  const float* fc_b = (const float*)d_in[2];
  const float* gat_W = (const float*)d_in[3];
  const float* gat_al = (const float*)d_in[4];
  const float* gat_ar = (const float*)d_in[5];
  const float* gat_b = (const float*)d_in[6];
  // d_in[7] = beta unused (reference returns Z_prev)
  const int* src = (const int*)d_in[8];
  const int* dst = (const int*)d_in[9];
  float* out = (float*)d_out;

  // ---- workspace layout (all 256B-aligned) ----
  char* w = (char*)d_ws;
  auto alloc = [&](size_t bytes) {
    char* p = w;
    w += (bytes + 255) & ~(size_t)255;
    return p;
  };
  unsigned short* hbf   = (unsigned short*)alloc((size_t)M_PAD * DIM_H * 2);
  unsigned short* fcWt  = (unsigned short*)alloc((size_t)DIM_H * DIM_IN * 2);
  unsigned short* gatWt = (unsigned short*)alloc((size_t)NUM_GNNS * DIM_H * DIM_H * 2);
  float* el    = (float*)alloc((size_t)N_NODES * 4);
  float* er    = (float*)alloc((size_t)N_NODES * 4);
  // counts+cursor one contiguous block: a single memset zeroes both (R2 lesson).
  int* counts  = (int*)alloc((size_t)2 * N_NODES * 4);
  int* cursor  = counts + N_NODES;
  int* indptr  = (int*)alloc((size_t)(N_NODES + 1) * 4);
  int* adjsrc  = (int*)alloc((size_t)N_EDGES * 4);
  // union region: Abf (feat bf16, GEMM0 only), later Z1 (bf16 hop-1 result)
  char* uni = alloc((size_t)M_PAD * DIM_IN * 2);   // 30.9 MB >= Z1's 20.6 MB
  unsigned short* Abf = (unsigned short*)uni;
  unsigned short* Z1  = (unsigned short*)uni;
  unsigned short* zbf = (unsigned short*)d_out;    // z lives in d_out during GAT layers

  // ---- CSR build ----
  hipMemsetAsync(counts, 0, sizeof(int) * 2 * N_NODES, stream);
  count_edges<<<(N_EDGES + 255) / 256, 256, 0, stream>>>(dst, counts);
  scan_kernel<<<1, 1024, 0, stream>>>(counts, indptr);
  fill_adj<<<(N_EDGES + 255) / 256, 256, 0, stream>>>(src, dst, indptr, cursor, adjsrc);

  // ---- bf16 prep ----
  convert_feat<<<(M_PAD * DIM_IN / 8 + 255) / 256, 256, 0, stream>>>(feat, Abf);
  transpose_bf16<<<dim3((DIM_IN + 255) / 256, DIM_H, 1), 256, 0, stream>>>(fc_W, fcWt, DIM_IN, DIM_H);
  transpose_bf16<<<dim3((DIM_H + 255) / 256, DIM_H, NUM_GNNS), 256, 0, stream>>>(gat_W, gatWt, DIM_H, DIM_H);

  dim3 ggrid(DIM_H / 128, M_PAD / 128);  // (4, 157)

  // h = feat @ fc_W + fc_b  -> hbf (bf16)
  gemm_mfma_bf16<<<ggrid, 256, 0, stream>>>(Abf, fcWt, fc_b, hbf, DIM_IN);

  int nwaveblocks = (N_NODES * 64 + 255) / 256;
  for (int l = 0; l < NUM_GNNS; ++l) {
    gemm_mfma_bf16<<<ggrid, 256, 0, stream>>>(hbf, gatWt + (size_t)l * DIM_H * DIM_H,
                                              nullptr, zbf, DIM_H);
    eler_bf<<<nwaveblocks, 256, 0, stream>>>(zbf, gat_al + (size_t)l * DIM_H,
                                             gat_ar + (size_t)l * DIM_H, el, er);
    gat_aggregate_bf<<<nwaveblocks, 256, 0, stream>>>(
        zbf, el, er, indptr, adjsrc, gat_b + (size_t)l * DIM_H, hbf);
  }

  // ---- 3 propagation hops, bf16 payloads, fp32 accumulate ----
  // Z0 = hbf (aggregate l=3 output). hbf free after hop1, uni free after hop2.
  propagate_bf<<<nwaveblocks, 256, 0, stream>>>(hbf, indptr, adjsrc, Z1, nullptr);
  propagate_bf<<<nwaveblocks, 256, 0, stream>>>(Z1, indptr, adjsrc, hbf, nullptr);
  propagate_bf<<<nwaveblocks, 256, 0, stream>>>(hbf, indptr, adjsrc, nullptr, out);
}

// Round 5
// 656.252 us; speedup vs baseline: 2.5273x; 1.0866x over previous
//
#include <hip/hip_runtime.h>
#include <math.h>

#define N_NODES 20000
#define M_PAD   20096   // 157 * 128
#define N_EDGES 320000
#define DIM_IN 768
#define DIM_H 512
#define NUM_GNNS 4
#define NEG_SLOPE 0.2f

typedef __attribute__((ext_vector_type(8))) short short8;
typedef __attribute__((ext_vector_type(4))) float f32x4;

#define GPTR(p) (const __attribute__((address_space(1))) void*)(p)
#define LPTR(p) (__attribute__((address_space(3))) void*)(p)

__device__ __forceinline__ float bf2f(unsigned int lo16) {
  return __uint_as_float(lo16 << 16);
}
__device__ __forceinline__ unsigned short f2bf(float f) {
  unsigned int u = __float_as_uint(f);
  u += 0x7FFFu + ((u >> 16) & 1u);   // round-to-nearest-even
  return (unsigned short)(u >> 16);
}
__device__ __forceinline__ void unpack8(uint4 v, float* f) {
  f[0] = bf2f(v.x & 0xffffu); f[1] = bf2f(v.x >> 16);
  f[2] = bf2f(v.y & 0xffffu); f[3] = bf2f(v.y >> 16);
  f[4] = bf2f(v.z & 0xffffu); f[5] = bf2f(v.z >> 16);
  f[6] = bf2f(v.w & 0xffffu); f[7] = bf2f(v.w >> 16);
}
__device__ __forceinline__ uint4 pack8(const float* o) {
  uint4 pv;
  pv.x = (unsigned)f2bf(o[0]) | ((unsigned)f2bf(o[1]) << 16);
  pv.y = (unsigned)f2bf(o[2]) | ((unsigned)f2bf(o[3]) << 16);
  pv.z = (unsigned)f2bf(o[4]) | ((unsigned)f2bf(o[5]) << 16);
  pv.w = (unsigned)f2bf(o[6]) | ((unsigned)f2bf(o[7]) << 16);
  return pv;
}

__device__ __forceinline__ float waveReduceSum(float v) {
#pragma unroll
  for (int off = 32; off > 0; off >>= 1) v += __shfl_xor(v, off, 64);
  return v;
}
__device__ __forceinline__ float waveReduceMax(float v) {
#pragma unroll
  for (int off = 32; off > 0; off >>= 1) v = fmaxf(v, __shfl_xor(v, off, 64));
  return v;
}

// ================= MFMA GEMM: Cbf[M_PAD,512](bf16) = A[M_PAD,K](bf16) @ Bt[512,K]^T (+bias) =====
__global__ __launch_bounds__(256) void gemm_mfma_bf16(
    const unsigned short* __restrict__ A,
    const unsigned short* __restrict__ Bt,
    const float* __restrict__ bias,
    unsigned short* __restrict__ Cbf,
    int K) {
  __shared__ __align__(16) unsigned short As[128 * 32];
  __shared__ __align__(16) unsigned short Bs[128 * 32];
  int tid = threadIdx.x;
  int wave = tid >> 6, lane = tid & 63;
  int wm = wave >> 1, wn = wave & 1;

  int rl = lane >> 2;
  int kc = (lane & 3) ^ ((lane >> 3) & 3);
  int r0 = 32 * wave;
  const unsigned short* gA0 = A + (size_t)(blockIdx.y * 128 + r0 + rl) * K + kc * 8;
  const unsigned short* gA1 = gA0 + (size_t)16 * K;
  const unsigned short* gB0 = Bt + (size_t)(blockIdx.x * 128 + r0 + rl) * K + kc * 8;
  const unsigned short* gB1 = gB0 + (size_t)16 * K;
  unsigned short* lA0 = As + r0 * 32;
  unsigned short* lA1 = As + (r0 + 16) * 32;
  unsigned short* lB0 = Bs + r0 * 32;
  unsigned short* lB1 = Bs + (r0 + 16) * 32;

  int mrow = lane & 15;
  int q = lane >> 4;
  int swz = (q ^ ((mrow >> 1) & 3)) * 8;
  const short8* ra = (const short8*)(As + (64 * wm + mrow) * 32 + swz);
  const short8* rb = (const short8*)(Bs + (64 * wn + mrow) * 32 + swz);

  f32x4 acc[4][4];
#pragma unroll
  for (int i = 0; i < 4; ++i)
#pragma unroll
    for (int j = 0; j < 4; ++j) acc[i][j] = (f32x4)(0.f);

  for (int k0 = 0; k0 < K; k0 += 32) {
    __syncthreads();
    __builtin_amdgcn_global_load_lds(GPTR(gA0 + k0), LPTR(lA0), 16, 0, 0);
    __builtin_amdgcn_global_load_lds(GPTR(gA1 + k0), LPTR(lA1), 16, 0, 0);
    __builtin_amdgcn_global_load_lds(GPTR(gB0 + k0), LPTR(lB0), 16, 0, 0);
    __builtin_amdgcn_global_load_lds(GPTR(gB1 + k0), LPTR(lB1), 16, 0, 0);
    __syncthreads();
    short8 a[4], b[4];
#pragma unroll
    for (int t = 0; t < 4; ++t) a[t] = ra[t * 64];
#pragma unroll
    for (int t = 0; t < 4; ++t) b[t] = rb[t * 64];
#pragma unroll
    for (int mt = 0; mt < 4; ++mt)
#pragma unroll
      for (int nt = 0; nt < 4; ++nt)
        acc[mt][nt] = __builtin_amdgcn_mfma_f32_16x16x32_bf16(a[mt], b[nt], acc[mt][nt], 0, 0, 0);
  }

  int colb = blockIdx.x * 128 + 64 * wn + (lane & 15);
  int rowb = blockIdx.y * 128 + 64 * wm + 4 * q;
#pragma unroll
  for (int nt = 0; nt < 4; ++nt) {
    int col = colb + 16 * nt;
    float bv = bias ? bias[col] : 0.f;
#pragma unroll
    for (int mt = 0; mt < 4; ++mt) {
      int row = rowb + 16 * mt;
#pragma unroll
      for (int i = 0; i < 4; ++i)
        Cbf[(size_t)(row + i) * DIM_H + col] = f2bf(acc[mt][nt][i] + bv);
    }
  }
}

// ================= conversions =================
__global__ void convert_feat(const float* __restrict__ feat, unsigned short* __restrict__ Abf) {
  int t = blockIdx.x * blockDim.x + threadIdx.x;
  const int CHUNKS = M_PAD * DIM_IN / 8;
  if (t >= CHUNKS) return;
  int row = t / (DIM_IN / 8);
  uint4 o;
  if (row < N_NODES) {
    const float4* p = (const float4*)(feat + (size_t)t * 8);
    float4 x = p[0], y = p[1];
    o.x = (unsigned)f2bf(x.x) | ((unsigned)f2bf(x.y) << 16);
    o.y = (unsigned)f2bf(x.z) | ((unsigned)f2bf(x.w) << 16);
    o.z = (unsigned)f2bf(y.x) | ((unsigned)f2bf(y.y) << 16);
    o.w = (unsigned)f2bf(y.z) | ((unsigned)f2bf(y.w) << 16);
  } else {
    o = make_uint4(0, 0, 0, 0);
  }
  ((uint4*)Abf)[t] = o;
}

__global__ void transpose_bf16(const float* __restrict__ in, unsigned short* __restrict__ out,
                               int R, int C) {
  int r = blockIdx.x * blockDim.x + threadIdx.x;
  int c = blockIdx.y;
  size_t base = (size_t)blockIdx.z * R * C;
  if (r < R) out[base + (size_t)c * R + r] = f2bf(in[base + (size_t)r * C + c]);
}

// ================= CSR build (dst -> src adjacency) =================
__global__ void count_edges(const int* __restrict__ dst, int* __restrict__ counts) {
  int k = blockIdx.x * blockDim.x + threadIdx.x;
  if (k < N_EDGES) atomicAdd(&counts[dst[k]], 1);
}

__global__ __launch_bounds__(1024) void scan_kernel(const int* __restrict__ counts,
                                                    int* __restrict__ indptr) {
  __shared__ int part[1024];
  int tid = threadIdx.x;
  const int CH = (N_NODES + 1023) / 1024;
  int base = tid * CH;
  int s = 0;
  for (int i = 0; i < CH; ++i) {
    int idx = base + i;
    if (idx < N_NODES) s += counts[idx];
  }
  part[tid] = s;
  __syncthreads();
  for (int off = 1; off < 1024; off <<= 1) {
    int v = (tid >= off) ? part[tid - off] : 0;
    __syncthreads();
    part[tid] += v;
    __syncthreads();
  }
  int run = (tid == 0) ? 0 : part[tid - 1];
  for (int i = 0; i < CH; ++i) {
    int idx = base + i;
    if (idx < N_NODES) {
      indptr[idx] = run;
      run += counts[idx];
      if (idx == N_NODES - 1) indptr[N_NODES] = run;
    }
  }
}

__global__ void fill_adj(const int* __restrict__ src, const int* __restrict__ dst,
                         const int* __restrict__ indptr, int* __restrict__ cursor,
                         int* __restrict__ adjsrc) {
  int k = blockIdx.x * blockDim.x + threadIdx.x;
  if (k < N_EDGES) {
    int d = dst[k];
    int pos = atomicAdd(&cursor[d], 1);
    adjsrc[indptr[d] + pos] = src[k];
  }
}

// ================= el/er from bf16 z =================
__global__ __launch_bounds__(256) void eler_bf(const unsigned short* __restrict__ zbf,
                                               const float* __restrict__ al,
                                               const float* __restrict__ ar,
                                               float* __restrict__ el, float* __restrict__ er) {
  int wid = (blockIdx.x * blockDim.x + threadIdx.x) >> 6;
  int lane = threadIdx.x & 63;
  if (wid >= N_NODES) return;
  uint4 zv = ((const uint4*)(zbf + (size_t)wid * DIM_H))[lane];
  float z[8];
  unpack8(zv, z);
  const float4* al4 = (const float4*)(al + lane * 8);
  const float4* ar4 = (const float4*)(ar + lane * 8);
  float4 a0 = al4[0], a1 = al4[1], r0 = ar4[0], r1 = ar4[1];
  float sl = z[0] * a0.x + z[1] * a0.y + z[2] * a0.z + z[3] * a0.w +
             z[4] * a1.x + z[5] * a1.y + z[6] * a1.z + z[7] * a1.w;
  float sr = z[0] * r0.x + z[1] * r0.y + z[2] * r0.z + z[3] * r0.w +
             z[4] * r1.x + z[5] * r1.y + z[6] * r1.z + z[7] * r1.w;
  sl = waveReduceSum(sl);
  sr = waveReduceSum(sr);
  if (lane == 0) { el[wid] = sl; er[wid] = sr; }
}

// ================= GAT edge softmax + aggregate (wave per dst), bf16 payload =================
// Pass 3 restructured for MLP: 64-edge chunks, per-lane weight precompute,
// shfl-broadcast ids/weights, 4 independent row-gathers in flight.
__global__ __launch_bounds__(256) void gat_aggregate_bf(
    const unsigned short* __restrict__ zbf, const float* __restrict__ el,
    const float* __restrict__ er, const int* __restrict__ indptr,
    const int* __restrict__ adjsrc, const float* __restrict__ bias,
    unsigned short* __restrict__ out_bf) {
  int v = (blockIdx.x * blockDim.x + threadIdx.x) >> 6;
  int lane = threadIdx.x & 63;
  if (v >= N_NODES) return;
  int begin = indptr[v], end = indptr[v + 1];
  float er_v = er[v];

  // pass 1: max (strided, el-only)
  float m = -INFINITY;
  for (int j = begin + lane; j < end; j += 64) {
    float e = el[adjsrc[j]] + er_v;
    e = (e >= 0.f) ? e : NEG_SLOPE * e;
    m = fmaxf(m, e);
  }
  m = waveReduceMax(m);

  // pass 2: denom (strided, el-only)
  float ssum = 0.f;
  for (int j = begin + lane; j < end; j += 64) {
    float e = el[adjsrc[j]] + er_v;
    e = (e >= 0.f) ? e : NEG_SLOPE * e;
    ssum += __expf(e - m);
  }
  float denom = waveReduceSum(ssum);
  float inv = (end > begin) ? 1.f / denom : 0.f;

  // pass 3: weighted accumulate, 4 rows in flight
  float acc[8] = {};
  for (int c = begin; c < end; c += 64) {
    int cc = min(64, end - c);
    int has = (c + lane < end);
    int sIdx = has ? adjsrc[c + lane] : 0;
    float e = has ? el[sIdx] + er_v : 0.f;
    e = (e >= 0.f) ? e : NEG_SLOPE * e;
    float wl = has ? __expf(e - m) * inv : 0.f;
    int t = 0;
    for (; t + 4 <= cc; t += 4) {
      int s0 = __shfl(sIdx, t + 0), s1 = __shfl(sIdx, t + 1);
      int s2 = __shfl(sIdx, t + 2), s3 = __shfl(sIdx, t + 3);
      float w0 = __shfl(wl, t + 0), w1 = __shfl(wl, t + 1);
      float w2 = __shfl(wl, t + 2), w3 = __shfl(wl, t + 3);
      uint4 z0 = ((const uint4*)(zbf + (size_t)s0 * DIM_H))[lane];
      uint4 z1 = ((const uint4*)(zbf + (size_t)s1 * DIM_H))[lane];
      uint4 z2 = ((const uint4*)(zbf + (size_t)s2 * DIM_H))[lane];
      uint4 z3 = ((const uint4*)(zbf + (size_t)s3 * DIM_H))[lane];
      float f0[8], f1[8], f2[8], f3[8];
      unpack8(z0, f0); unpack8(z1, f1); unpack8(z2, f2); unpack8(z3, f3);
#pragma unroll
      for (int i = 0; i < 8; ++i)
        acc[i] += w0 * f0[i] + w1 * f1[i] + w2 * f2[i] + w3 * f3[i];
    }
    for (; t < cc; ++t) {
      int s0 = __shfl(sIdx, t);
      float w0 = __shfl(wl, t);
      uint4 z0 = ((const uint4*)(zbf + (size_t)s0 * DIM_H))[lane];
      float f0[8];
      unpack8(z0, f0);
#pragma unroll
      for (int i = 0; i < 8; ++i) acc[i] += w0 * f0[i];
    }
  }
  const float4* b4 = (const float4*)(bias + lane * 8);
  float4 b0 = b4[0], b1 = b4[1];
  float o[8] = {acc[0] + b0.x, acc[1] + b0.y, acc[2] + b0.z, acc[3] + b0.w,
                acc[4] + b1.x, acc[5] + b1.y, acc[6] + b1.z, acc[7] + b1.w};
  ((uint4*)(out_bf + (size_t)v * DIM_H))[lane] = pack8(o);
}

// ======== A_hat hop (bf16 payload, fp32 accumulate), 4 rows in flight ========
__global__ __launch_bounds__(256) void propagate_bf(const unsigned short* __restrict__ zin,
                                                    const int* __restrict__ indptr,
                                                    const int* __restrict__ adjsrc,
                                                    unsigned short* __restrict__ out_bf,
                                                    float* __restrict__ out_f32) {
  int v = (blockIdx.x * blockDim.x + threadIdx.x) >> 6;
  int lane = threadIdx.x & 63;
  if (v >= N_NODES) return;
  uint4 sv = ((const uint4*)(zin + (size_t)v * DIM_H))[lane];
  float acc[8];
  unpack8(sv, acc);
  int begin = indptr[v], end = indptr[v + 1];
  for (int c = begin; c < end; c += 64) {
    int cc = min(64, end - c);
    int sIdx = (c + lane < end) ? adjsrc[c + lane] : 0;
    int t = 0;
    for (; t + 4 <= cc; t += 4) {
      int s0 = __shfl(sIdx, t + 0), s1 = __shfl(sIdx, t + 1);
      int s2 = __shfl(sIdx, t + 2), s3 = __shfl(sIdx, t + 3);
      uint4 z0 = ((const uint4*)(zin + (size_t)s0 * DIM_H))[lane];
      uint4 z1 = ((const uint4*)(zin + (size_t)s1 * DIM_H))[lane];
      uint4 z2 = ((const uint4*)(zin + (size_t)s2 * DIM_H))[lane];
      uint4 z3 = ((const uint4*)(zin + (size_t)s3 * DIM_H))[lane];
      float f0[8], f1[8], f2[8], f3[8];
      unpack8(z0, f0); unpack8(z1, f1); unpack8(z2, f2); unpack8(z3, f3);
#pragma unroll
      for (int i = 0; i < 8; ++i) acc[i] += f0[i] + f1[i] + f2[i] + f3[i];
    }
    for (; t < cc; ++t) {
      int s0 = __shfl(sIdx, t);
      uint4 z0 = ((const uint4*)(zin + (size_t)s0 * DIM_H))[lane];
      float f0[8];
      unpack8(z0, f0);
#pragma unroll
      for (int i = 0; i < 8; ++i) acc[i] += f0[i];
    }
  }
  if (out_bf) {
    ((uint4*)(out_bf + (size_t)v * DIM_H))[lane] = pack8(acc);
  } else {
    float4* fr = (float4*)(out_f32 + (size_t)v * DIM_H + lane * 8);
    fr[0] = make_float4(acc[0], acc[1], acc[2], acc[3]);
    fr[1] = make_float4(acc[4], acc[5], acc[6], acc[7]);
  }
}

// ================= launch =================
extern "C" void kernel_launch(void* const* d_in, const int* in_sizes, int n_in,
                              void* d_out, int out_size, void* d_ws, size_t ws_size,
                              hipStream_t stream) {
  const float* feat = (const float*)d_in[0];
  const float* fc_W = (const float*)d_in[1];
  const float* fc_b = (const float*)d_in[2];
  const float* gat_W = (const float*)d_in[3];
  const float* gat_al = (const float*)d_in[4];
  const float* gat_ar = (const float*)d_in[5];
  const float* gat_b = (const float*)d_in[6];
  // d_in[7] = beta unused (reference returns Z_prev)
  const int* src = (const int*)d_in[8];
  const int* dst = (const int*)d_in[9];
  float* out = (float*)d_out;

  char* w = (char*)d_ws;
  auto alloc = [&](size_t bytes) {
    char* p = w;
    w += (bytes + 255) & ~(size_t)255;
    return p;
  };
  unsigned short* hbf   = (unsigned short*)alloc((size_t)M_PAD * DIM_H * 2);
  unsigned short* fcWt  = (unsigned short*)alloc((size_t)DIM_H * DIM_IN * 2);
  unsigned short* gatWt = (unsigned short*)alloc((size_t)NUM_GNNS * DIM_H * DIM_H * 2);
  float* el    = (float*)alloc((size_t)N_NODES * 4);
  float* er    = (float*)alloc((size_t)N_NODES * 4);
  int* counts  = (int*)alloc((size_t)2 * N_NODES * 4);   // counts+cursor contiguous (R2 lesson)
  int* cursor  = counts + N_NODES;
  int* indptr  = (int*)alloc((size_t)(N_NODES + 1) * 4);
  int* adjsrc  = (int*)alloc((size_t)N_EDGES * 4);
  char* uni = alloc((size_t)M_PAD * DIM_IN * 2);   // Abf (30.9 MB), later Z1 (20.6 MB)
  unsigned short* Abf = (unsigned short*)uni;
  unsigned short* Z1  = (unsigned short*)uni;
  unsigned short* zbf = (unsigned short*)d_out;

  // ---- CSR build ----
  hipMemsetAsync(counts, 0, sizeof(int) * 2 * N_NODES, stream);
  count_edges<<<(N_EDGES + 255) / 256, 256, 0, stream>>>(dst, counts);
  scan_kernel<<<1, 1024, 0, stream>>>(counts, indptr);
  fill_adj<<<(N_EDGES + 255) / 256, 256, 0, stream>>>(src, dst, indptr, cursor, adjsrc);

  // ---- bf16 prep ----
  convert_feat<<<(M_PAD * DIM_IN / 8 + 255) / 256, 256, 0, stream>>>(feat, Abf);
  transpose_bf16<<<dim3((DIM_IN + 255) / 256, DIM_H, 1), 256, 0, stream>>>(fc_W, fcWt, DIM_IN, DIM_H);
  transpose_bf16<<<dim3((DIM_H + 255) / 256, DIM_H, NUM_GNNS), 256, 0, stream>>>(gat_W, gatWt, DIM_H, DIM_H);

  dim3 ggrid(DIM_H / 128, M_PAD / 128);  // (4, 157)

  gemm_mfma_bf16<<<ggrid, 256, 0, stream>>>(Abf, fcWt, fc_b, hbf, DIM_IN);

  int nwaveblocks = (N_NODES * 64 + 255) / 256;
  for (int l = 0; l < NUM_GNNS; ++l) {
    gemm_mfma_bf16<<<ggrid, 256, 0, stream>>>(hbf, gatWt + (size_t)l * DIM_H * DIM_H,
                                              nullptr, zbf, DIM_H);
    eler_bf<<<nwaveblocks, 256, 0, stream>>>(zbf, gat_al + (size_t)l * DIM_H,
                                             gat_ar + (size_t)l * DIM_H, el, er);
    gat_aggregate_bf<<<nwaveblocks, 256, 0, stream>>>(
        zbf, el, er, indptr, adjsrc, gat_b + (size_t)l * DIM_H, hbf);
  }

  // ---- 3 propagation hops, bf16 payloads, fp32 accumulate ----
  propagate_bf<<<nwaveblocks, 256, 0, stream>>>(hbf, indptr, adjsrc, Z1, nullptr);
  propagate_bf<<<nwaveblocks, 256, 0, stream>>>(Z1, indptr, adjsrc, hbf, nullptr);
  propagate_bf<<<nwaveblocks, 256, 0, stream>>>(hbf, indptr, adjsrc, nullptr, out);
}